// Round 4
// baseline (102.924 us; speedup 1.0000x reference)
//
#include <hip/hip_runtime.h>

#define BATCH 8
#define NPTS 9225
#define MQ 4096
#define CAP 64
#define GRID 32
#define NCELLS (GRID * GRID)   // 1024, cell = 1/32 = 0.03125 > r = 0.03

__device__ __forceinline__ int cell_of(float x, float y) {
  int cx = (int)(x * (float)GRID);
  int cy = (int)(y * (float)GRID);
  cx = min(max(cx, 0), GRID - 1);
  cy = min(max(cy, 0), GRID - 1);
  return cy * GRID + cx;
}

// One block per batch: LDS histogram -> LDS scan -> scatter. Replaces 4 kernels.
__global__ __launch_bounds__(1024) void build_kernel(
    const float* __restrict__ data,
    int* __restrict__ cell_starts,   // [B][NCELLS+1]
    float2* __restrict__ sdata, int* __restrict__ sidx) {
  __shared__ int hist[NCELLS];
  __shared__ int cursor[NCELLS];
  const int b = blockIdx.x;
  const int t = threadIdx.x;
  hist[t] = 0;
  __syncthreads();

  const float2* dp = (const float2*)data + (size_t)b * NPTS;
  float2 pts[10];
  int cells[10];
  int np = 0;
  for (int i = t; i < NPTS; i += 1024) {
    const float2 p = dp[i];
    const int c = cell_of(p.x, p.y);
    pts[np] = p;
    cells[np] = c;
    ++np;
    atomicAdd(&hist[c], 1);
  }
  __syncthreads();

  const int v = hist[t];
  for (int off = 1; off < NCELLS; off <<= 1) {
    const int u = (t >= off) ? hist[t - off] : 0;
    __syncthreads();
    hist[t] += u;
    __syncthreads();
  }
  const int incl = hist[t];
  const int excl = incl - v;
  cursor[t] = excl;
  cell_starts[b * (NCELLS + 1) + t] = excl;
  if (t == NCELLS - 1) cell_starts[b * (NCELLS + 1) + NCELLS] = incl;
  __syncthreads();

  float2* sd = sdata + (size_t)b * NPTS;
  int* si = sidx + (size_t)b * NPTS;
  for (int k = 0; k < np; ++k) {
    const int pos = atomicAdd(&cursor[cells[k]], 1);
    sd[pos] = pts[k];
    si[pos] = t + k * 1024;  // original batch-local index
  }
}

// One wave per query; 3 cell-rows concatenated into one lane-mapped stream.
__global__ __launch_bounds__(256) void search_kernel(
    const float* __restrict__ queries, const float* __restrict__ radius_p,
    const int* __restrict__ cell_starts, const float2* __restrict__ sdata,
    const int* __restrict__ sidx, int* __restrict__ nbr_idx,
    int* __restrict__ counts) {
#pragma clang fp contract(off)
  __shared__ int hitbuf[4][CAP];
  const int wave_g = (blockIdx.x * blockDim.x + threadIdx.x) >> 6;
  const int lane = threadIdx.x & 63;
  const int w = (threadIdx.x >> 6) & 3;
  if (wave_g >= BATCH * MQ) return;
  const int q = wave_g;
  const int b = q >> 12;  // MQ = 4096
  const float r = radius_p[0];
  const float r2 = r * r;
  const float2 qv = ((const float2*)queries)[q];
  const float qx = qv.x, qy = qv.y;
  const float qn = qx * qx + qy * qy;  // mul,mul,add — no fma (matches np)

  const int cx = min(max((int)(qx * (float)GRID), 0), GRID - 1);
  const int cy = min(max((int)(qy * (float)GRID), 0), GRID - 1);
  const int x0 = max(cx - 1, 0), x1 = min(cx + 1, GRID - 1);
  const int y0 = max(cy - 1, 0), y1 = min(cy + 1, GRID - 1);

  const int csbase = b * (NCELLS + 1);
  int rstart[3], rlen[3];
  int nr = 0;
  for (int y = y0; y <= y1; ++y) {
    const int s0 = cell_starts[csbase + y * GRID + x0];
    const int s1 = cell_starts[csbase + y * GRID + x1 + 1];
    rstart[nr] = s0;
    rlen[nr] = s1 - s0;
    ++nr;
  }
  for (int k = nr; k < 3; ++k) { rstart[k] = 0; rlen[k] = 0; }
  const int L0 = rlen[0];
  const int L01 = L0 + rlen[1];
  const int T = L01 + rlen[2];

  const unsigned long long below = (1ull << lane) - 1ull;
  const float2* sd = sdata + (size_t)b * NPTS;
  const int* si = sidx + (size_t)b * NPTS;
  int h = 0;

  for (int base = 0; base < T; base += 64) {
    const int p = base + lane;
    const bool act = (p < T);
    int i;
    if (p < L0)        i = rstart[0] + p;
    else if (p < L01)  i = rstart[1] + (p - L0);
    else               i = rstart[2] + (p - L01);
    if (!act) i = 0;  // safe address
    const float2 pt = sd[i];
    const int id = si[i];
    const float dx = pt.x, dy = pt.y;
    const float dn = dx * dx + dy * dy;            // mul,mul,add — no fma
    const float cross = qx * dx + qy * dy;         // mul,mul,add — no fma
    const float s = (qn + dn) - 2.0f * cross;      // matches np op order
    const bool in = act && (s <= r2);
    const unsigned long long mask = __ballot(in);
    if (mask != 0ull) {
      if (in) {
        const int pos = h + __popcll(mask & below);
        if (pos < CAP) hitbuf[w][pos] = id;
      }
      h += __popcll(mask);
    }
  }

  // gather (same-wave LDS RAW is in-order)
  int v = (lane < h && lane < CAP) ? hitbuf[w][lane] : 0x7fffffff;

  // bitonic sort: k=2..32 sorts each 32-half (low asc, high desc=all-MAX)
#pragma unroll
  for (int k = 2; k <= 32; k <<= 1) {
#pragma unroll
    for (int j = k >> 1; j >= 1; j >>= 1) {
      const int other = __shfl_xor(v, j, 64);
      const bool keep_min = (((lane & k) == 0) == ((lane & j) == 0));
      v = keep_min ? min(v, other) : max(v, other);
    }
  }
  if (h > 32) {  // final 64-merge only needed if hits spill past lane 31
#pragma unroll
    for (int j = 32; j >= 1; j >>= 1) {
      const int other = __shfl_xor(v, j, 64);
      const bool keep_min = ((lane & j) == 0);
      v = keep_min ? min(v, other) : max(v, other);
    }
  }

  nbr_idx[(size_t)q * CAP + lane] = (v == 0x7fffffff) ? -1 : v;
  if (lane == 0) counts[q] = h;
}

// Per-batch exclusive scan of 4096 counts -> row_splits[b][0..4096]
__global__ __launch_bounds__(256) void scan_kernel(const int* __restrict__ counts,
                                                   int* __restrict__ row_splits) {
  const int b = blockIdx.x;
  const int t = threadIdx.x;
  const int T = 256;
  const int PER = MQ / T;  // 16
  __shared__ int partial[T];
  const int* c = counts + b * MQ;
  int local[PER];
  int sum = 0;
#pragma unroll
  for (int k = 0; k < PER; ++k) { local[k] = c[t * PER + k]; sum += local[k]; }
  partial[t] = sum;
  __syncthreads();
  for (int off = 1; off < T; off <<= 1) {
    int u = (t >= off) ? partial[t - off] : 0;
    __syncthreads();
    partial[t] += u;
    __syncthreads();
  }
  const int excl = (t == 0) ? 0 : partial[t - 1];
  int* rs = row_splits + b * (MQ + 1);
  if (t == 0) rs[0] = 0;
  int run = excl;
#pragma unroll
  for (int k = 0; k < PER; ++k) { run += local[k]; rs[t * PER + k + 1] = run; }
}

extern "C" void kernel_launch(void* const* d_in, const int* in_sizes, int n_in,
                              void* d_out, int out_size, void* d_ws, size_t ws_size,
                              hipStream_t stream) {
  const float* data    = (const float*)d_in[0];
  const float* queries = (const float*)d_in[1];
  const float* radius  = (const float*)d_in[2];
  int* out        = (int*)d_out;
  int* nbr_idx    = out;                       // BATCH*MQ*CAP
  int* row_splits = out + BATCH * MQ * CAP;    // BATCH*(MQ+1)

  // workspace layout (ints)
  int* counts      = (int*)d_ws;                         // 32768
  int* cell_starts = counts + BATCH * MQ;                // 8200
  int* sidx        = cell_starts + BATCH * (NCELLS + 1); // 73800
  float2* sdata    = (float2*)(sidx + BATCH * NPTS);     // 73800 float2

  hipLaunchKernelGGL(build_kernel, dim3(BATCH), dim3(1024), 0, stream,
                     data, cell_starts, sdata, sidx);
  hipLaunchKernelGGL(search_kernel, dim3(BATCH * MQ / 4), dim3(256), 0, stream,
                     queries, radius, cell_starts, sdata, sidx, nbr_idx, counts);
  hipLaunchKernelGGL(scan_kernel, dim3(BATCH), dim3(256), 0, stream,
                     counts, row_splits);
}